// Round 1
// 1298.213 us; speedup vs baseline: 1.0459x; 1.0459x over previous
//
#include <hip/hip_runtime.h>
#include <hip/hip_bf16.h>

typedef __bf16 bf16_t;
typedef bf16_t bf16x8 __attribute__((ext_vector_type(8)));
typedef bf16_t bf16x4v __attribute__((ext_vector_type(4)));
typedef bf16_t bf16x2v __attribute__((ext_vector_type(2)));
typedef float f32x4 __attribute__((ext_vector_type(4)));

#define N_NODES 500000
#define N_GRAPHS 4096
#define NODE_SIZE 512
#define GLOBAL_SIZE 256
#define HIDDEN_SIZE 1024
#define INPUT_SIZE 768

__device__ __forceinline__ void async16(const bf16_t* g, bf16_t* l) {
    __builtin_amdgcn_global_load_lds(
        (__attribute__((address_space(1))) void*)(const_cast<bf16_t*>(g)),
        (__attribute__((address_space(3))) void*)(l), 16, 0, 0);
}

__device__ __forceinline__ f32x4 ntload4(const float* p) {
    return __builtin_nontemporal_load((const f32x4*)p);
}

// ---------------------------------------------------------------------------
// Weight convert+transpose: W[K][N] f32 -> Wt[N][K] bf16.
// LDS 32x32 tiled transpose: coalesced reads AND writes (old version read
// with 4KB stride -> 64B fetch per 4B used).
// K, N are multiples of 32 for both weight matrices.
// ---------------------------------------------------------------------------
__global__ __launch_bounds__(256)
void cvt_transpose(const float* __restrict__ W, bf16_t* __restrict__ Wt,
                   int K, int N) {
    __shared__ float t[32][33];  // +1 pad: conflict-free transposed read
    const int tk = blockIdx.x * 32;  // k-tile origin
    const int tn = blockIdx.y * 32;  // n-tile origin
    const int lx = threadIdx.x & 31;
    const int ly = threadIdx.x >> 5;  // 0..7

#pragma unroll
    for (int i = 0; i < 4; ++i) {
        const int kl = ly + i * 8;
        t[kl][lx] = W[(size_t)(tk + kl) * N + tn + lx];
    }
    __syncthreads();
#pragma unroll
    for (int i = 0; i < 4; ++i) {
        const int nl = ly + i * 8;
        Wt[(size_t)(tn + nl) * K + tk + lx] = (bf16_t)t[lx][nl];
    }
}

// ---------------------------------------------------------------------------
// Per-graph mean of x rows (batch sorted -> contiguous segment per graph),
// fused with concat: A[g] = [bf16(u[g]) | bf16(mean_g)]  (A is [4096][768] bf16)
// One block (128 threads) per graph; float4 streaming loads (16 B/lane).
//
// v2: explicit 4-row software pipeline. The old 2-row unroll consumed loads
// issued in the SAME iteration -> full vmcnt drain (~HBM latency) every 2
// rows. Now adds consume the PREVIOUS iteration's loads while 4 fresh loads
// stay in flight (steady-state vmcnt(4), never 0). Nontemporal: x has zero
// reuse; don't pollute L2/L3 ahead of the GEMMs.
// ---------------------------------------------------------------------------
__global__ __launch_bounds__(128)
void mean_concat_kernel(const float* __restrict__ x, const float* __restrict__ u,
                        const int* __restrict__ batch, bf16_t* __restrict__ A) {
    const int g = blockIdx.x;
    const int tid = threadIdx.x;

    // u part: 256 floats -> bf16, 2 per thread
    {
        const float2 uv = *(const float2*)(u + (size_t)g * GLOBAL_SIZE + tid * 2);
        bf16x2v o;
        o[0] = (bf16_t)uv.x;
        o[1] = (bf16_t)uv.y;
        *(bf16x2v*)(A + (size_t)g * INPUT_SIZE + tid * 2) = o;
    }

    // segment bounds via binary search (uniform across threads)
    int start, end;
    {
        int lo = 0, hi = N_NODES;
        while (lo < hi) { int m = (lo + hi) >> 1; if (batch[m] < g) lo = m + 1; else hi = m; }
        start = lo;
        hi = N_NODES;
        while (lo < hi) { int m = (lo + hi) >> 1; if (batch[m] < g + 1) lo = m + 1; else hi = m; }
        end = lo;
    }

    const int rows = end - start;
    const float* pr = x + (size_t)start * NODE_SIZE + (tid << 2);

    f32x4 s0 = {0.f, 0.f, 0.f, 0.f};
    f32x4 s1 = {0.f, 0.f, 0.f, 0.f};
    f32x4 s2 = {0.f, 0.f, 0.f, 0.f};
    f32x4 s3 = {0.f, 0.f, 0.f, 0.f};

    int r = 0;
    if (rows >= 4) {
        // prefetch 4 rows
        f32x4 v0 = ntload4(pr);
        f32x4 v1 = ntload4(pr + NODE_SIZE);
        f32x4 v2 = ntload4(pr + 2 * NODE_SIZE);
        f32x4 v3 = ntload4(pr + 3 * NODE_SIZE);
        pr += 4 * NODE_SIZE;
        for (r = 4; r + 4 <= rows; r += 4) {
            const f32x4 n0 = ntload4(pr);
            const f32x4 n1 = ntload4(pr + NODE_SIZE);
            const f32x4 n2 = ntload4(pr + 2 * NODE_SIZE);
            const f32x4 n3 = ntload4(pr + 3 * NODE_SIZE);
            pr += 4 * NODE_SIZE;
            s0 += v0; s1 += v1; s2 += v2; s3 += v3;
            v0 = n0; v1 = n1; v2 = n2; v3 = n3;
        }
        s0 += v0; s1 += v1; s2 += v2; s3 += v3;
    }
    for (; r < rows; ++r) {
        s0 += ntload4(x + (size_t)(start + r) * NODE_SIZE + (tid << 2));
    }

    const f32x4 st = (s0 + s1) + (s2 + s3);
    const float inv = rows > 0 ? 1.f / (float)rows : 0.f;
    bf16x4v o;
    o[0] = (bf16_t)(st[0] * inv);
    o[1] = (bf16_t)(st[1] * inv);
    o[2] = (bf16_t)(st[2] * inv);
    o[3] = (bf16_t)(st[3] * inv);
    *(bf16x4v*)(A + (size_t)g * INPUT_SIZE + GLOBAL_SIZE + (tid << 2)) = o;
}

// ---------------------------------------------------------------------------
// GEMM: C[M][N] = act(A[M][K] @ Bt[N][K]^T + bias), bf16 inputs, fp32 acc.
// m97 recipe: 128x128 tile, BK=32, global_load_lds width-16, mfma 16x16x32.
// 4 waves in 2x2, each wave 64x64 via 4x4 mfma accs.  (unchanged this round)
// ---------------------------------------------------------------------------
template <bool SELU_ACT, bool OUT_BF16>
__global__ __launch_bounds__(256)
void gemm_bt(const bf16_t* __restrict__ A, const bf16_t* __restrict__ Bt,
             const float* __restrict__ bias, void* __restrict__ Cv,
             int M, int N, int K) {
    constexpr int BM = 128, BN = 128, BK = 32;
    __shared__ bf16_t Al[BM * BK];
    __shared__ bf16_t Bl[BN * BK];

    const int tid = threadIdx.x;
    const int wave = tid >> 6, lane = tid & 63;
    const int quad = lane >> 4, rr = lane & 15;
    const int wm = (wave >> 1) * 64, wn = (wave & 1) * 64;
    const int tm = blockIdx.x * BM, tn = blockIdx.y * BN;

    f32x4 acc[4][4] = {};

    for (int bk = 0; bk < K; bk += BK) {
        // stage A tile: 128 rows x 32 cols bf16 = 512 x 16B chunks, 2/thread
#pragma unroll
        for (int i = 0; i < 2; ++i) {
            int linear = i * 256 + tid;
            int row = linear >> 2, kq = linear & 3;
            async16(A + (size_t)(tm + row) * K + bk + kq * 8, &Al[linear * 8]);
        }
#pragma unroll
        for (int i = 0; i < 2; ++i) {
            int linear = i * 256 + tid;
            int row = linear >> 2, kq = linear & 3;
            async16(Bt + (size_t)(tn + row) * K + bk + kq * 8, &Bl[linear * 8]);
        }
        __syncthreads();  // drains vmcnt incl. global_load_lds

        bf16x8 af[4], bfr[4];
#pragma unroll
        for (int mi = 0; mi < 4; ++mi)
            af[mi] = *(const bf16x8*)&Al[(wm + mi * 16 + rr) * BK + quad * 8];
#pragma unroll
        for (int ni = 0; ni < 4; ++ni)
            bfr[ni] = *(const bf16x8*)&Bl[(wn + ni * 16 + rr) * BK + quad * 8];
#pragma unroll
        for (int mi = 0; mi < 4; ++mi)
#pragma unroll
            for (int ni = 0; ni < 4; ++ni)
                acc[mi][ni] = __builtin_amdgcn_mfma_f32_16x16x32_bf16(
                    af[mi], bfr[ni], acc[mi][ni], 0, 0, 0);
        __syncthreads();
    }

    // epilogue: D row = quad*4+e, col = rr (per 16x16 sub-tile)
    float* Cf = (float*)Cv;
    bf16_t* Cb = (bf16_t*)Cv;
#pragma unroll
    for (int ni = 0; ni < 4; ++ni) {
        const int col = tn + wn + ni * 16 + rr;
        const float bv = bias[col];
#pragma unroll
        for (int mi = 0; mi < 4; ++mi) {
#pragma unroll
            for (int e = 0; e < 4; ++e) {
                const int row = tm + wm + mi * 16 + quad * 4 + e;
                float val = acc[mi][ni][e] + bv;
                if (SELU_ACT) {
                    val = val > 0.f ? 1.0507009873554805f * val
                                    : 1.7580993408473766f * (__expf(val) - 1.f);
                }
                if (OUT_BF16) Cb[(size_t)row * N + col] = (bf16_t)val;
                else          Cf[(size_t)row * N + col] = val;
            }
        }
    }
}

extern "C" void kernel_launch(void* const* d_in, const int* in_sizes, int n_in,
                              void* d_out, int out_size, void* d_ws, size_t ws_size,
                              hipStream_t stream) {
    const float* x     = (const float*)d_in[0];
    // d_in[1] edge_index, d_in[2] edge_attr: unused by reference
    const float* u     = (const float*)d_in[3];
    const int*   batch = (const int*)d_in[4];
    const float* W1    = (const float*)d_in[5];
    const float* b1    = (const float*)d_in[6];
    const float* W2    = (const float*)d_in[7];
    const float* b2    = (const float*)d_in[8];
    float* out = (float*)d_out;

    char* ws = (char*)d_ws;
    bf16_t* A1  = (bf16_t*)(ws);                                  // 4096*768  bf16 = 6 MB
    bf16_t* W1t = (bf16_t*)(ws + 6291456);                        // 1024*768  bf16
    bf16_t* W2t = (bf16_t*)(ws + 6291456 + 1572864);              // 256*1024  bf16
    bf16_t* h   = (bf16_t*)(ws + 8388608);                        // 4096*1024 bf16 = 8 MB

    // big streaming read first
    mean_concat_kernel<<<N_GRAPHS, 128, 0, stream>>>(x, u, batch, A1);

    cvt_transpose<<<dim3(INPUT_SIZE / 32, HIDDEN_SIZE / 32), 256, 0, stream>>>(
        W1, W1t, INPUT_SIZE, HIDDEN_SIZE);
    cvt_transpose<<<dim3(HIDDEN_SIZE / 32, GLOBAL_SIZE / 32), 256, 0, stream>>>(
        W2, W2t, HIDDEN_SIZE, GLOBAL_SIZE);

    gemm_bt<true, true><<<dim3(N_GRAPHS / 128, HIDDEN_SIZE / 128), 256, 0, stream>>>(
        A1, W1t, b1, h, N_GRAPHS, HIDDEN_SIZE, INPUT_SIZE);
    gemm_bt<false, false><<<dim3(N_GRAPHS / 128, GLOBAL_SIZE / 128), 256, 0, stream>>>(
        h, W2t, b2, out, N_GRAPHS, GLOBAL_SIZE, HIDDEN_SIZE);
}